// Round 3
// baseline (1383.349 us; speedup 1.0000x reference)
//
#include <hip/hip_runtime.h>
#include <hip/hip_bf16.h>

// ---------------------------------------------------------------------------
// GNN Residual Feature Extractor
//   x = embed(type features)                       [N,32]
//   x1 = gcn(x, W1)+b1                             [N,64]
//   h  = relu(gcn(relu(x1),W2)+b2)                 [N,128]
//   h  = relu(gcn(h,W3)+b3) + x1                   [N,64]
//   out = segment_mean(h, batch)                   [100,64]
//
// gcn agg commutes with weight multiply; aggregate on narrow side.
// Tables are PRE-SCALED by dinv (and pre-activated) by their producers, so
// gathers are pure  out_i = dv_i * (t'_i + sum_s t'_s)  — no per-edge dinv
// loads, no per-edge relu.
//
// CSR build: 2-pass LDS-staged binning (bin = dst>>10). Pass A stages edges
// in LDS and flushes wave-coalesced 512B runs (full L2 lines; write-back
// ~= logical size, vs 5-15x amplification for direct scatter). Pass B
// finalizes CSR per bin inside an L2-resident window.
// ---------------------------------------------------------------------------

#define THREADS 256
#define BINSHIFT 10
#define EPBA 4096        // edges per block, pass A
#define CAP 64           // LDS stage capacity per bin (<= wavefront size)

// ---------------- pass 0: bin histogram ----------------
__global__ __launch_bounds__(THREADS)
void k_hist(const int* __restrict__ dst, int* __restrict__ binent, int nb, int e) {
    extern __shared__ int h[];
    int t = threadIdx.x;
    for (int i = t; i < nb; i += THREADS) h[i] = 0;
    __syncthreads();
    int stride = gridDim.x * THREADS;
    for (int i = blockIdx.x * THREADS + t; i < e; i += stride)
        atomicAdd(&h[dst[i] >> BINSHIFT], 1);
    __syncthreads();
    for (int i = t; i < nb; i += THREADS)
        if (h[i]) atomicAdd(&binent[i], h[i]);
}

// ---------------- pass 0b: scan bins (single block, nb<=128) ----------------
__global__ __launch_bounds__(128)
void k_binscan(const int* __restrict__ binent, int* __restrict__ binptr,
               int* __restrict__ bincur, int nb, int e) {
    __shared__ int lds[128];
    int t = threadIdx.x;
    int v = (t < nb) ? binent[t] : 0;
    lds[t] = v;
    __syncthreads();
    for (int off = 1; off < 128; off <<= 1) {
        int a = (t >= off) ? lds[t - off] : 0;
        __syncthreads();
        lds[t] += a;
        __syncthreads();
    }
    if (t < nb) {
        int excl = lds[t] - v;
        binptr[t] = excl;
        bincur[t] = excl;
    }
    if (t == 0) binptr[nb] = e;
}

// ---------------- pass A: LDS-staged bin scatter ----------------
__global__ __launch_bounds__(THREADS)
void k_binscatter(const int* __restrict__ src, const int* __restrict__ dst,
                  int* __restrict__ bincur, int2* __restrict__ pairs,
                  int nb, int e) {
    extern __shared__ int smem[];
    int* cnt = smem;                          // nb
    int2* stage = (int2*)(smem + 2 * ((nb + 1) & ~1)); // nb*CAP, 8B aligned
    int t = threadIdx.x;
    for (int i = t; i < nb; i += THREADS) cnt[i] = 0;
    __syncthreads();
    int lo = blockIdx.x * EPBA;
    int hi = min(lo + EPBA, e);
    for (int i = lo + t; i < hi; i += THREADS) {
        int s = src[i], d = dst[i];
        int b = d >> BINSHIFT;
        int pos = atomicAdd(&cnt[b], 1);
        if (pos < CAP) stage[b * CAP + pos] = make_int2(s, d);
        else {  // rare overflow: 1-entry slow path
            int gp = atomicAdd(&bincur[b], 1);
            pairs[gp] = make_int2(s, d);
        }
    }
    __syncthreads();
    // flush: one wave per bin -> contiguous coalesced runs
    int wid = t >> 6, lane = t & 63;
    for (int b = wid; b < nb; b += (THREADS / 64)) {
        int n = min(cnt[b], CAP);
        int gbase = 0;
        if (lane == 0 && n > 0) gbase = atomicAdd(&bincur[b], n);
        gbase = __shfl(gbase, 0, 64);
        if (lane < n) pairs[gbase + lane] = stage[b * CAP + lane];
    }
}

// ---------------- pass B: per-bin CSR finalize ----------------
__global__ __launch_bounds__(THREADS)
void k_bincsr(const int2* __restrict__ pairs, const int* __restrict__ binptr,
              int* __restrict__ rowptr, float* __restrict__ dinv,
              int* __restrict__ srcs, int n, int nb, int e) {
    __shared__ int lcnt[1024];
    __shared__ int lofs[1024];
    __shared__ int wsum[THREADS];
    int b = blockIdx.x, t = threadIdx.x;
    int e0 = binptr[b], e1 = binptr[b + 1];
    int n0 = b << BINSHIFT;
    for (int i = t; i < 1024; i += THREADS) lcnt[i] = 0;
    __syncthreads();
    for (int j = e0 + t; j < e1; j += THREADS)
        atomicAdd(&lcnt[pairs[j].y - n0], 1);
    __syncthreads();
    // block scan of 1024 counts (4 per thread)
    int c0 = lcnt[4 * t + 0], c1 = lcnt[4 * t + 1];
    int c2 = lcnt[4 * t + 2], c3 = lcnt[4 * t + 3];
    int s = c0 + c1 + c2 + c3;
    wsum[t] = s;
    __syncthreads();
    for (int off = 1; off < THREADS; off <<= 1) {
        int a = (t >= off) ? wsum[t - off] : 0;
        __syncthreads();
        wsum[t] += a;
        __syncthreads();
    }
    int excl = wsum[t] - s;
    lofs[4 * t + 0] = excl;
    lofs[4 * t + 1] = excl + c0;
    lofs[4 * t + 2] = excl + c0 + c1;
    lofs[4 * t + 3] = excl + c0 + c1 + c2;
    __syncthreads();
    for (int i = t; i < 1024; i += THREADS) {
        int node = n0 + i;
        if (node < n) {
            rowptr[node] = e0 + lofs[i];
            dinv[node] = rsqrtf((float)lcnt[i] + 1.0f);
        }
    }
    if (b == nb - 1 && t == 0) rowptr[n] = e;
    __syncthreads();
    for (int j = e0 + t; j < e1; j += THREADS) {
        int2 p = pairs[j];
        int pos = e0 + atomicAdd(&lofs[p.y - n0], 1);
        srcs[pos] = p.x;
    }
}

// ---------------- embedding: x[idx[r]] = dinv * (f[r] @ W + b) ----------------
template <int K>
__global__ __launch_bounds__(THREADS)
void k_embed(const float* __restrict__ f, const float* __restrict__ W,
             const float* __restrict__ b, const int* __restrict__ idx,
             const float* __restrict__ dinv, int rows, float* __restrict__ x) {
    int g = blockIdx.x * THREADS + threadIdx.x;
    int r = g >> 5, c = g & 31;
    if (r >= rows) return;
    int node = idx[r];
    float a = b[c];
#pragma unroll
    for (int k = 0; k < K; ++k) a += f[r * K + k] * W[k * 32 + c];
    x[(size_t)node * 32 + c] = dinv[node] * a;
}

// ---------------- gather aggregation (tables pre-scaled by dinv) ----------------
// out[i] = dv_i * (tbl[i] + sum_s tbl[s])  [+bias][relu][+resid]
template <int C, bool HASBIAS, bool OUTRELU, bool HASRES>
__global__ __launch_bounds__(THREADS)
void k_gather(const float* __restrict__ tbl, const int* __restrict__ rowptr,
              const int* __restrict__ srcs, const float* __restrict__ dinv,
              const float* __restrict__ bias, const float* __restrict__ resid,
              float* __restrict__ out, int n) {
    int gt = blockIdx.x * THREADS + threadIdx.x;
    int node = gt >> 6;
    int lane = threadIdx.x & 63;
    if (node >= n) return;
    float dv = dinv[node];
    int beg = rowptr[node], end = rowptr[node + 1];

    if (C == 64) {
        float acc = tbl[(size_t)node * 64 + lane];  // self term (pre-scaled)
        int j = beg;
        for (; j + 4 <= end; j += 4) {
            int s0 = srcs[j], s1 = srcs[j + 1], s2 = srcs[j + 2], s3 = srcs[j + 3];
            float v0 = tbl[(size_t)s0 * 64 + lane];
            float v1 = tbl[(size_t)s1 * 64 + lane];
            float v2 = tbl[(size_t)s2 * 64 + lane];
            float v3 = tbl[(size_t)s3 * 64 + lane];
            acc += v0; acc += v1; acc += v2; acc += v3;
        }
        for (; j < end; ++j) acc += tbl[(size_t)srcs[j] * 64 + lane];
        float r = dv * acc;
        if (HASBIAS) r += bias[lane];
        if (OUTRELU) r = fmaxf(r, 0.f);
        if (HASRES) r += resid[(size_t)node * 64 + lane];
        out[(size_t)node * 64 + lane] = r;
    } else {  // C == 32 : two half-waves take alternate edges
        int col = lane & 31, half = lane >> 5;
        float acc = 0.f;
        int j = beg + half;
        for (; j + 4 <= end; j += 4) {
            int s0 = srcs[j], s1 = srcs[j + 2];
            float v0 = tbl[(size_t)s0 * 32 + col];
            float v1 = tbl[(size_t)s1 * 32 + col];
            acc += v0; acc += v1;
        }
        for (; j < end; j += 2) acc += tbl[(size_t)srcs[j] * 32 + col];
        acc += __shfl_down(acc, 32, 64);
        if (half == 0) {
            float r = dv * (acc + tbl[(size_t)node * 32 + col]);
            if (HASBIAS) r += bias[col];
            if (OUTRELU) r = fmaxf(r, 0.f);
            if (HASRES) r += resid[(size_t)node * 32 + col];
            out[(size_t)node * 32 + col] = r;
        }
    }
}

// ---------------- dense matmul: out[N,FOUT] = in[N,FIN] @ W + b ----------------
// EXTRA: 0 = plain; 1 = also write out2 = dinv*relu(out) (raw out kept);
//        2 = main out scaled by dinv.
template <int FIN, int FOUT, bool HASBIAS, bool OUTRELU, int EXTRA>
__global__ __launch_bounds__(THREADS)
void k_mm(const float* __restrict__ xin, const float* __restrict__ W,
          const float* __restrict__ bias, const float* __restrict__ dinv,
          float* __restrict__ out, float* __restrict__ out2, int nrows) {
    constexpr int FINQ = FIN / 4;
    __shared__ float wlds[FOUT * FIN];
    int tid = threadIdx.x;
    for (int i = tid; i < FIN * FOUT; i += THREADS) {
        int k = i / FOUT, c = i % FOUT;
        wlds[c * FIN + k] = W[i];  // store W^T
    }
    __syncthreads();
    int row = blockIdx.x * THREADS + tid;
    if (row >= nrows) return;

    float4 xreg[FINQ];
    const float4* xr = reinterpret_cast<const float4*>(xin + (size_t)row * FIN);
#pragma unroll
    for (int q = 0; q < FINQ; ++q) xreg[q] = xr[q];

    float dv = (EXTRA != 0) ? dinv[row] : 0.f;

    const float4* w4 = reinterpret_cast<const float4*>(wlds);
    for (int c0 = 0; c0 < FOUT; c0 += 4) {
        float a0 = HASBIAS ? bias[c0 + 0] : 0.f;
        float a1 = HASBIAS ? bias[c0 + 1] : 0.f;
        float a2 = HASBIAS ? bias[c0 + 2] : 0.f;
        float a3 = HASBIAS ? bias[c0 + 3] : 0.f;
#pragma unroll
        for (int q = 0; q < FINQ; ++q) {
            float4 xv = xreg[q];
            float4 w0 = w4[(c0 + 0) * FINQ + q];
            float4 w1 = w4[(c0 + 1) * FINQ + q];
            float4 w2 = w4[(c0 + 2) * FINQ + q];
            float4 w3 = w4[(c0 + 3) * FINQ + q];
            a0 += xv.x * w0.x + xv.y * w0.y + xv.z * w0.z + xv.w * w0.w;
            a1 += xv.x * w1.x + xv.y * w1.y + xv.z * w1.z + xv.w * w1.w;
            a2 += xv.x * w2.x + xv.y * w2.y + xv.z * w2.z + xv.w * w2.w;
            a3 += xv.x * w3.x + xv.y * w3.y + xv.z * w3.z + xv.w * w3.w;
        }
        if (OUTRELU) {
            a0 = fmaxf(a0, 0.f); a1 = fmaxf(a1, 0.f);
            a2 = fmaxf(a2, 0.f); a3 = fmaxf(a3, 0.f);
        }
        if (EXTRA == 2) { a0 *= dv; a1 *= dv; a2 *= dv; a3 *= dv; }
        float4 o = {a0, a1, a2, a3};
        *reinterpret_cast<float4*>(out + (size_t)row * FOUT + c0) = o;
        if (EXTRA == 1) {
            float4 o2 = {dv * fmaxf(a0, 0.f), dv * fmaxf(a1, 0.f),
                         dv * fmaxf(a2, 0.f), dv * fmaxf(a3, 0.f)};
            *reinterpret_cast<float4*>(out2 + (size_t)row * FOUT + c0) = o2;
        }
    }
}

// ---------------- segment mean pool ----------------
__global__ __launch_bounds__(THREADS)
void k_pool(const float* __restrict__ h, const int* __restrict__ batch,
            float* __restrict__ sums, float* __restrict__ cnts, int n) {
    int c = threadIdx.x & 63;
    int rq = threadIdx.x >> 6;  // 0..3
    int r0 = blockIdx.x * THREADS;
    int rend = min(r0 + THREADS, n);
    int curg = -1;
    float acc = 0.f, cacc = 0.f;
    for (int r = r0 + rq; r < rend; r += 4) {
        int g = batch[r];
        if (g != curg) {
            if (curg >= 0) {
                atomicAdd(&sums[(size_t)curg * 64 + c], acc);
                if (c == 0) atomicAdd(&cnts[curg], cacc);
            }
            curg = g; acc = 0.f; cacc = 0.f;
        }
        acc += h[(size_t)r * 64 + c];
        cacc += 1.f;
    }
    if (curg >= 0) {
        atomicAdd(&sums[(size_t)curg * 64 + c], acc);
        if (c == 0) atomicAdd(&cnts[curg], cacc);
    }
}

__global__ __launch_bounds__(THREADS)
void k_div(const float* __restrict__ sums, const float* __restrict__ cnts,
           float* __restrict__ out, int total) {
    int i = blockIdx.x * THREADS + threadIdx.x;
    if (i < total) out[i] = sums[i] / cnts[i >> 6];
}

// ---------------------------------------------------------------------------
static inline size_t alignup(size_t v) { return (v + 255) & ~(size_t)255; }

extern "C" void kernel_launch(void* const* d_in, const int* in_sizes, int n_in,
                              void* d_out, int out_size, void* d_ws, size_t ws_size,
                              hipStream_t stream) {
    const float* ev_f  = (const float*)d_in[0];
    const float* cs_f  = (const float*)d_in[1];
    const float* tr_f  = (const float*)d_in[2];
    const float* env_f = (const float*)d_in[3];
    const int*   ei    = (const int*)d_in[4];
    const int*   ev_i  = (const int*)d_in[5];
    const int*   cs_i  = (const int*)d_in[6];
    const int*   tr_i  = (const int*)d_in[7];
    const int*   env_i = (const int*)d_in[8];
    const int*   batch = (const int*)d_in[9];
    const float* W_ev = (const float*)d_in[10]; const float* b_ev = (const float*)d_in[11];
    const float* W_cs = (const float*)d_in[12]; const float* b_cs = (const float*)d_in[13];
    const float* W_tr = (const float*)d_in[14]; const float* b_tr = (const float*)d_in[15];
    const float* W_env= (const float*)d_in[16]; const float* b_env= (const float*)d_in[17];
    const float* W1 = (const float*)d_in[18]; const float* b1 = (const float*)d_in[19];
    const float* W2 = (const float*)d_in[20]; const float* b2 = (const float*)d_in[21];
    const float* W3 = (const float*)d_in[22]; const float* b3 = (const float*)d_in[23];

    const int E_ = in_sizes[4] / 2;
    const int N_ = in_sizes[9];
    const int n_ev  = in_sizes[5];
    const int n_cs  = in_sizes[6];
    const int n_tr  = in_sizes[7];
    const int n_env = in_sizes[8];
    const int ngr   = out_size / 64;  // 100 graphs

    const int* e_src = ei;
    const int* e_dst = ei + E_;

    const int NB = (N_ + (1 << BINSHIFT) - 1) >> BINSHIFT;  // 98 bins

    // ---- workspace carve-up ----
    char* p = (char*)d_ws;
    int*   binent = (int*)p;    p += alignup((size_t)NB * 4);
    int*   binptr = (int*)p;    p += alignup(((size_t)NB + 1) * 4);
    int*   bincur = (int*)p;    p += alignup((size_t)NB * 4);
    int*   rowptr = (int*)p;    p += alignup(((size_t)N_ + 1) * 4);
    float* dinv   = (float*)p;  p += alignup((size_t)N_ * 4);
    int*   srcs   = (int*)p;    p += alignup((size_t)E_ * 4);
    float* x      = (float*)p;  p += alignup((size_t)N_ * 32 * 4);
    float* x1     = (float*)p;  p += alignup((size_t)N_ * 64 * 4);
    float* bufB   = (float*)p;  p += alignup((size_t)N_ * 64 * 4);
    float* bufA   = (float*)p;  p += alignup((size_t)N_ * 128 * 4);
    float* sums   = (float*)p;  p += alignup((size_t)ngr * 64 * 4);
    float* cnts   = (float*)p;  p += alignup((size_t)ngr * 4);

    // pairs (E int2 = 25.6 MB) and x1s (N*64*4 = 25.6 MB) both alias bufA
    // (51.2 MB). Lifetimes: pairs dies at k_bincsr; x1s lives conv1-mm ->
    // conv2-gather; bufA first written by conv2-mm. No overlap.
    int2*  pairs = (int2*)bufA;
    float* x1s   = (float*)bufA;

    const int nblk = (N_ + THREADS - 1) / THREADS;
    const int ablk = (E_ + EPBA - 1) / EPBA;                        // 782
    const int gblk = ((size_t)N_ * 64 + THREADS - 1) / THREADS;     // wave/node

    const size_t hist_lds = (size_t)NB * 4;
    const size_t scat_lds = (size_t)((NB + 1) & ~1) * 2 * 4 + (size_t)NB * CAP * 8;

    // ---- zero accumulated buffers (fresh every call) ----
    hipMemsetAsync(binent, 0, (size_t)NB * 4, stream);
    hipMemsetAsync(sums, 0, (size_t)ngr * 64 * 4, stream);
    hipMemsetAsync(cnts, 0, (size_t)ngr * 4, stream);

    // ---- CSR build ----
    k_hist<<<512, THREADS, hist_lds, stream>>>(e_dst, binent, NB, E_);
    k_binscan<<<1, 128, 0, stream>>>(binent, binptr, bincur, NB, E_);
    k_binscatter<<<ablk, THREADS, scat_lds, stream>>>(e_src, e_dst, bincur, pairs, NB, E_);
    k_bincsr<<<NB, THREADS, 0, stream>>>(pairs, binptr, rowptr, dinv, srcs, N_, NB, E_);

    // ---- embeddings -> x [N,32] (pre-scaled by dinv) ----
    k_embed<6><<<((size_t)n_ev  * 32 + THREADS - 1) / THREADS, THREADS, 0, stream>>>(ev_f,  W_ev,  b_ev,  ev_i,  dinv, n_ev,  x);
    k_embed<4><<<((size_t)n_cs  * 32 + THREADS - 1) / THREADS, THREADS, 0, stream>>>(cs_f,  W_cs,  b_cs,  cs_i,  dinv, n_cs,  x);
    k_embed<2><<<((size_t)n_tr  * 32 + THREADS - 1) / THREADS, THREADS, 0, stream>>>(tr_f,  W_tr,  b_tr,  tr_i,  dinv, n_tr,  x);
    k_embed<5><<<((size_t)n_env * 32 + THREADS - 1) / THREADS, THREADS, 0, stream>>>(env_f, W_env, b_env, env_i, dinv, n_env, x);

    // ---- conv1: agg(x) @ W1 + b1 -> x1 ; also x1s = dinv*relu(x1) ----
    k_gather<32, false, false, false><<<gblk, THREADS, 0, stream>>>(
        x, rowptr, srcs, dinv, nullptr, nullptr, bufB, N_);
    k_mm<32, 64, true, false, 1><<<nblk, THREADS, 0, stream>>>(bufB, W1, b1, dinv, x1, x1s, N_);

    // ---- conv2: relu( agg(x1s) @ W2 + b2 ) -> bufA [N,128] ----
    k_gather<64, false, false, false><<<gblk, THREADS, 0, stream>>>(
        x1s, rowptr, srcs, dinv, nullptr, nullptr, bufB, N_);
    k_mm<64, 128, true, true, 0><<<nblk, THREADS, 0, stream>>>(bufB, W2, b2, nullptr, bufA, nullptr, N_);

    // ---- conv3: t3s = dinv*(bufA @ W3); h = relu(agg(t3s)+b3)+x1 -> bufA ----
    k_mm<128, 64, false, false, 2><<<nblk, THREADS, 0, stream>>>(bufA, W3, nullptr, dinv, bufB, nullptr, N_);
    k_gather<64, true, true, true><<<gblk, THREADS, 0, stream>>>(
        bufB, rowptr, srcs, dinv, b3, x1, bufA, N_);

    // ---- pool ----
    k_pool<<<nblk, THREADS, 0, stream>>>(bufA, batch, sums, cnts, N_);
    k_div<<<(out_size + THREADS - 1) / THREADS, THREADS, 0, stream>>>(sums, cnts, (float*)d_out, out_size);
}

// Round 4
// 742.714 us; speedup vs baseline: 1.8626x; 1.8626x over previous
//
#include <hip/hip_runtime.h>
#include <hip/hip_bf16.h>

// ---------------------------------------------------------------------------
// GNN Residual Feature Extractor
//   x = embed(type features)                       [N,32]
//   x1 = gcn(x, W1)+b1                             [N,64]
//   h  = relu(gcn(relu(x1),W2)+b2)                 [N,128]
//   h  = relu(gcn(h,W3)+b3) + x1                   [N,64]
//   out = segment_mean(h, batch)                   [100,64]
//
// gcn agg commutes with weight multiply; aggregate on narrow side.
// Tables are PRE-SCALED by dinv (and pre-activated) by their producers, so
// gathers are pure  out_i = dv_i * (t'_i + sum_s t'_s).
//
// CSR build: atomic-free two-pass radix partition (bin = dst>>10).
//   pass1 k_partcnt:  exact per-(block,bin) counts via LDS histogram
//   scan  k_scanrows: exclusive scan per bin across blocks (+ bin totals)
//         k_binscan:  scan bin totals -> binptr
//   pass2 k_partwrite: deterministic placement, zero global atomics,
//                      dense per-(block,bin) runs -> full-line write-back
//   (R3's flush-atomic design serialized on 98 contended bincur words:
//    683us with all pipes idle. This removes every global atomic.)
// ---------------------------------------------------------------------------

#define THREADS 256
#define BINSHIFT 10
#define EPBA 4096        // edges per partition block
#define SCANCH 8         // k_scanrows: values per thread (supports <=2048 blocks)

// ---------------- pass 1: per-(block,bin) exact counts ----------------
__global__ __launch_bounds__(THREADS)
void k_partcnt(const int* __restrict__ dst, int* __restrict__ counts,
               int nblk_part, int nb, int e) {
    extern __shared__ int h[];
    int t = threadIdx.x;
    for (int i = t; i < nb; i += THREADS) h[i] = 0;
    __syncthreads();
    int lo = blockIdx.x * EPBA;
    int hi = min(lo + EPBA, e);
    for (int i = lo + t; i < hi; i += THREADS)
        atomicAdd(&h[dst[i] >> BINSHIFT], 1);
    __syncthreads();
    for (int i = t; i < nb; i += THREADS)
        counts[(size_t)i * nblk_part + blockIdx.x] = h[i];
}

// ---------------- scan each bin's row of per-block counts ----------------
__global__ __launch_bounds__(THREADS)
void k_scanrows(int* __restrict__ counts, int* __restrict__ bintot, int nblk_part) {
    __shared__ int wsum[THREADS];
    int* row = counts + (size_t)blockIdx.x * nblk_part;
    int t = threadIdx.x;
    int base = t * SCANCH;
    int v[SCANCH];
    int s = 0;
#pragma unroll
    for (int k = 0; k < SCANCH; ++k) {
        v[k] = (base + k < nblk_part) ? row[base + k] : 0;
        s += v[k];
    }
    wsum[t] = s;
    __syncthreads();
    for (int off = 1; off < THREADS; off <<= 1) {
        int a = (t >= off) ? wsum[t - off] : 0;
        __syncthreads();
        wsum[t] += a;
        __syncthreads();
    }
    int run = wsum[t] - s;  // exclusive
#pragma unroll
    for (int k = 0; k < SCANCH; ++k) {
        int c = v[k];
        if (base + k < nblk_part) row[base + k] = run;
        run += c;
    }
    if (t == THREADS - 1) bintot[blockIdx.x] = run;
}

// ---------------- scan bin totals (single block, nb<=128) ----------------
__global__ __launch_bounds__(128)
void k_binscan(const int* __restrict__ bintot, int* __restrict__ binptr,
               int nb, int e) {
    __shared__ int lds[128];
    int t = threadIdx.x;
    int v = (t < nb) ? bintot[t] : 0;
    lds[t] = v;
    __syncthreads();
    for (int off = 1; off < 128; off <<= 1) {
        int a = (t >= off) ? lds[t - off] : 0;
        __syncthreads();
        lds[t] += a;
        __syncthreads();
    }
    if (t < nb) binptr[t] = lds[t] - v;  // exclusive
    if (t == 0) binptr[nb] = e;
}

// ---------------- pass 2: deterministic partition write ----------------
__global__ __launch_bounds__(THREADS)
void k_partwrite(const int* __restrict__ src, const int* __restrict__ dst,
                 const int* __restrict__ binptr, const int* __restrict__ counts,
                 int nblk_part, int2* __restrict__ pairs, int nb, int e) {
    extern __shared__ int smem[];
    int* base = smem;       // nb
    int* cnt  = smem + nb;  // nb
    int t = threadIdx.x;
    for (int i = t; i < nb; i += THREADS) {
        base[i] = binptr[i] + counts[(size_t)i * nblk_part + blockIdx.x];
        cnt[i] = 0;
    }
    __syncthreads();
    int lo = blockIdx.x * EPBA;
    int hi = min(lo + EPBA, e);
    for (int i = lo + t; i < hi; i += THREADS) {
        int s = src[i], d = dst[i];
        int b = d >> BINSHIFT;
        int pos = atomicAdd(&cnt[b], 1);   // LDS only
        pairs[base[b] + pos] = make_int2(s, d);
    }
}

// ---------------- per-bin CSR finalize ----------------
__global__ __launch_bounds__(THREADS)
void k_bincsr(const int2* __restrict__ pairs, const int* __restrict__ binptr,
              int* __restrict__ rowptr, float* __restrict__ dinv,
              int* __restrict__ srcs, int n, int nb, int e) {
    __shared__ int lcnt[1024];
    __shared__ int lofs[1024];
    __shared__ int wsum[THREADS];
    int b = blockIdx.x, t = threadIdx.x;
    int e0 = binptr[b], e1 = binptr[b + 1];
    int n0 = b << BINSHIFT;
    for (int i = t; i < 1024; i += THREADS) lcnt[i] = 0;
    __syncthreads();
    for (int j = e0 + t; j < e1; j += THREADS)
        atomicAdd(&lcnt[pairs[j].y - n0], 1);
    __syncthreads();
    int c0 = lcnt[4 * t + 0], c1 = lcnt[4 * t + 1];
    int c2 = lcnt[4 * t + 2], c3 = lcnt[4 * t + 3];
    int s = c0 + c1 + c2 + c3;
    wsum[t] = s;
    __syncthreads();
    for (int off = 1; off < THREADS; off <<= 1) {
        int a = (t >= off) ? wsum[t - off] : 0;
        __syncthreads();
        wsum[t] += a;
        __syncthreads();
    }
    int excl = wsum[t] - s;
    lofs[4 * t + 0] = excl;
    lofs[4 * t + 1] = excl + c0;
    lofs[4 * t + 2] = excl + c0 + c1;
    lofs[4 * t + 3] = excl + c0 + c1 + c2;
    __syncthreads();
    for (int i = t; i < 1024; i += THREADS) {
        int node = n0 + i;
        if (node < n) {
            rowptr[node] = e0 + lofs[i];
            dinv[node] = rsqrtf((float)lcnt[i] + 1.0f);
        }
    }
    if (b == nb - 1 && t == 0) rowptr[n] = e;
    __syncthreads();
    for (int j = e0 + t; j < e1; j += THREADS) {
        int2 p = pairs[j];
        int pos = e0 + atomicAdd(&lofs[p.y - n0], 1);
        srcs[pos] = p.x;
    }
}

// ---------------- embedding: x[idx[r]] = dinv * (f[r] @ W + b) ----------------
template <int K>
__global__ __launch_bounds__(THREADS)
void k_embed(const float* __restrict__ f, const float* __restrict__ W,
             const float* __restrict__ b, const int* __restrict__ idx,
             const float* __restrict__ dinv, int rows, float* __restrict__ x) {
    int g = blockIdx.x * THREADS + threadIdx.x;
    int r = g >> 5, c = g & 31;
    if (r >= rows) return;
    int node = idx[r];
    float a = b[c];
#pragma unroll
    for (int k = 0; k < K; ++k) a += f[r * K + k] * W[k * 32 + c];
    x[(size_t)node * 32 + c] = dinv[node] * a;
}

// ---------------- gather aggregation (tables pre-scaled by dinv) ----------------
// out[i] = dv_i * (tbl[i] + sum_s tbl[s])  [+bias][relu][+resid]
template <int C, bool HASBIAS, bool OUTRELU, bool HASRES>
__global__ __launch_bounds__(THREADS)
void k_gather(const float* __restrict__ tbl, const int* __restrict__ rowptr,
              const int* __restrict__ srcs, const float* __restrict__ dinv,
              const float* __restrict__ bias, const float* __restrict__ resid,
              float* __restrict__ out, int n) {
    int gt = blockIdx.x * THREADS + threadIdx.x;
    int node = gt >> 6;
    int lane = threadIdx.x & 63;
    if (node >= n) return;
    float dv = dinv[node];
    int beg = rowptr[node], end = rowptr[node + 1];

    if (C == 64) {
        float acc = tbl[(size_t)node * 64 + lane];  // self term (pre-scaled)
        int j = beg;
        for (; j + 4 <= end; j += 4) {
            int s0 = srcs[j], s1 = srcs[j + 1], s2 = srcs[j + 2], s3 = srcs[j + 3];
            float v0 = tbl[(size_t)s0 * 64 + lane];
            float v1 = tbl[(size_t)s1 * 64 + lane];
            float v2 = tbl[(size_t)s2 * 64 + lane];
            float v3 = tbl[(size_t)s3 * 64 + lane];
            acc += v0; acc += v1; acc += v2; acc += v3;
        }
        for (; j < end; ++j) acc += tbl[(size_t)srcs[j] * 64 + lane];
        float r = dv * acc;
        if (HASBIAS) r += bias[lane];
        if (OUTRELU) r = fmaxf(r, 0.f);
        if (HASRES) r += resid[(size_t)node * 64 + lane];
        out[(size_t)node * 64 + lane] = r;
    } else {  // C == 32 : two half-waves take alternate edges
        int col = lane & 31, half = lane >> 5;
        float acc = 0.f;
        int j = beg + half;
        for (; j + 4 <= end; j += 4) {
            int s0 = srcs[j], s1 = srcs[j + 2];
            float v0 = tbl[(size_t)s0 * 32 + col];
            float v1 = tbl[(size_t)s1 * 32 + col];
            acc += v0; acc += v1;
        }
        for (; j < end; j += 2) acc += tbl[(size_t)srcs[j] * 32 + col];
        acc += __shfl_down(acc, 32, 64);
        if (half == 0) {
            float r = dv * (acc + tbl[(size_t)node * 32 + col]);
            if (HASBIAS) r += bias[col];
            if (OUTRELU) r = fmaxf(r, 0.f);
            if (HASRES) r += resid[(size_t)node * 32 + col];
            out[(size_t)node * 32 + col] = r;
        }
    }
}

// ---------------- dense matmul: out[N,FOUT] = in[N,FIN] @ W + b ----------------
// EXTRA: 0 = plain; 1 = also write out2 = dinv*relu(out) (raw out kept);
//        2 = main out scaled by dinv.
template <int FIN, int FOUT, bool HASBIAS, bool OUTRELU, int EXTRA>
__global__ __launch_bounds__(THREADS)
void k_mm(const float* __restrict__ xin, const float* __restrict__ W,
          const float* __restrict__ bias, const float* __restrict__ dinv,
          float* __restrict__ out, float* __restrict__ out2, int nrows) {
    constexpr int FINQ = FIN / 4;
    __shared__ float wlds[FOUT * FIN];
    int tid = threadIdx.x;
    for (int i = tid; i < FIN * FOUT; i += THREADS) {
        int k = i / FOUT, c = i % FOUT;
        wlds[c * FIN + k] = W[i];  // store W^T
    }
    __syncthreads();
    int row = blockIdx.x * THREADS + tid;
    if (row >= nrows) return;

    float4 xreg[FINQ];
    const float4* xr = reinterpret_cast<const float4*>(xin + (size_t)row * FIN);
#pragma unroll
    for (int q = 0; q < FINQ; ++q) xreg[q] = xr[q];

    float dv = (EXTRA != 0) ? dinv[row] : 0.f;

    const float4* w4 = reinterpret_cast<const float4*>(wlds);
    for (int c0 = 0; c0 < FOUT; c0 += 4) {
        float a0 = HASBIAS ? bias[c0 + 0] : 0.f;
        float a1 = HASBIAS ? bias[c0 + 1] : 0.f;
        float a2 = HASBIAS ? bias[c0 + 2] : 0.f;
        float a3 = HASBIAS ? bias[c0 + 3] : 0.f;
#pragma unroll
        for (int q = 0; q < FINQ; ++q) {
            float4 xv = xreg[q];
            float4 w0 = w4[(c0 + 0) * FINQ + q];
            float4 w1 = w4[(c0 + 1) * FINQ + q];
            float4 w2 = w4[(c0 + 2) * FINQ + q];
            float4 w3 = w4[(c0 + 3) * FINQ + q];
            a0 += xv.x * w0.x + xv.y * w0.y + xv.z * w0.z + xv.w * w0.w;
            a1 += xv.x * w1.x + xv.y * w1.y + xv.z * w1.z + xv.w * w1.w;
            a2 += xv.x * w2.x + xv.y * w2.y + xv.z * w2.z + xv.w * w2.w;
            a3 += xv.x * w3.x + xv.y * w3.y + xv.z * w3.z + xv.w * w3.w;
        }
        if (OUTRELU) {
            a0 = fmaxf(a0, 0.f); a1 = fmaxf(a1, 0.f);
            a2 = fmaxf(a2, 0.f); a3 = fmaxf(a3, 0.f);
        }
        if (EXTRA == 2) { a0 *= dv; a1 *= dv; a2 *= dv; a3 *= dv; }
        float4 o = {a0, a1, a2, a3};
        *reinterpret_cast<float4*>(out + (size_t)row * FOUT + c0) = o;
        if (EXTRA == 1) {
            float4 o2 = {dv * fmaxf(a0, 0.f), dv * fmaxf(a1, 0.f),
                         dv * fmaxf(a2, 0.f), dv * fmaxf(a3, 0.f)};
            *reinterpret_cast<float4*>(out2 + (size_t)row * FOUT + c0) = o2;
        }
    }
}

// ---------------- segment mean pool ----------------
__global__ __launch_bounds__(THREADS)
void k_pool(const float* __restrict__ h, const int* __restrict__ batch,
            float* __restrict__ sums, float* __restrict__ cnts, int n) {
    int c = threadIdx.x & 63;
    int rq = threadIdx.x >> 6;  // 0..3
    int r0 = blockIdx.x * THREADS;
    int rend = min(r0 + THREADS, n);
    int curg = -1;
    float acc = 0.f, cacc = 0.f;
    for (int r = r0 + rq; r < rend; r += 4) {
        int g = batch[r];
        if (g != curg) {
            if (curg >= 0) {
                atomicAdd(&sums[(size_t)curg * 64 + c], acc);
                if (c == 0) atomicAdd(&cnts[curg], cacc);
            }
            curg = g; acc = 0.f; cacc = 0.f;
        }
        acc += h[(size_t)r * 64 + c];
        cacc += 1.f;
    }
    if (curg >= 0) {
        atomicAdd(&sums[(size_t)curg * 64 + c], acc);
        if (c == 0) atomicAdd(&cnts[curg], cacc);
    }
}

__global__ __launch_bounds__(THREADS)
void k_div(const float* __restrict__ sums, const float* __restrict__ cnts,
           float* __restrict__ out, int total) {
    int i = blockIdx.x * THREADS + threadIdx.x;
    if (i < total) out[i] = sums[i] / cnts[i >> 6];
}

// ---------------------------------------------------------------------------
static inline size_t alignup(size_t v) { return (v + 255) & ~(size_t)255; }

extern "C" void kernel_launch(void* const* d_in, const int* in_sizes, int n_in,
                              void* d_out, int out_size, void* d_ws, size_t ws_size,
                              hipStream_t stream) {
    const float* ev_f  = (const float*)d_in[0];
    const float* cs_f  = (const float*)d_in[1];
    const float* tr_f  = (const float*)d_in[2];
    const float* env_f = (const float*)d_in[3];
    const int*   ei    = (const int*)d_in[4];
    const int*   ev_i  = (const int*)d_in[5];
    const int*   cs_i  = (const int*)d_in[6];
    const int*   tr_i  = (const int*)d_in[7];
    const int*   env_i = (const int*)d_in[8];
    const int*   batch = (const int*)d_in[9];
    const float* W_ev = (const float*)d_in[10]; const float* b_ev = (const float*)d_in[11];
    const float* W_cs = (const float*)d_in[12]; const float* b_cs = (const float*)d_in[13];
    const float* W_tr = (const float*)d_in[14]; const float* b_tr = (const float*)d_in[15];
    const float* W_env= (const float*)d_in[16]; const float* b_env= (const float*)d_in[17];
    const float* W1 = (const float*)d_in[18]; const float* b1 = (const float*)d_in[19];
    const float* W2 = (const float*)d_in[20]; const float* b2 = (const float*)d_in[21];
    const float* W3 = (const float*)d_in[22]; const float* b3 = (const float*)d_in[23];

    const int E_ = in_sizes[4] / 2;
    const int N_ = in_sizes[9];
    const int n_ev  = in_sizes[5];
    const int n_cs  = in_sizes[6];
    const int n_tr  = in_sizes[7];
    const int n_env = in_sizes[8];
    const int ngr   = out_size / 64;  // 100 graphs

    const int* e_src = ei;
    const int* e_dst = ei + E_;

    const int NB   = (N_ + (1 << BINSHIFT) - 1) >> BINSHIFT;  // 98 bins
    const int ablk = (E_ + EPBA - 1) / EPBA;                  // 782 partition blocks

    // ---- workspace carve-up ----
    char* p = (char*)d_ws;
    int*   counts = (int*)p;    p += alignup((size_t)NB * ablk * 4);
    int*   bintot = (int*)p;    p += alignup((size_t)NB * 4);
    int*   binptr = (int*)p;    p += alignup(((size_t)NB + 1) * 4);
    int*   rowptr = (int*)p;    p += alignup(((size_t)N_ + 1) * 4);
    float* dinv   = (float*)p;  p += alignup((size_t)N_ * 4);
    int*   srcs   = (int*)p;    p += alignup((size_t)E_ * 4);
    float* x      = (float*)p;  p += alignup((size_t)N_ * 32 * 4);
    float* x1     = (float*)p;  p += alignup((size_t)N_ * 64 * 4);
    float* bufB   = (float*)p;  p += alignup((size_t)N_ * 64 * 4);
    float* bufA   = (float*)p;  p += alignup((size_t)N_ * 128 * 4);
    float* sums   = (float*)p;  p += alignup((size_t)ngr * 64 * 4);
    float* cnts   = (float*)p;  p += alignup((size_t)ngr * 4);

    // pairs (E int2 = 25.6 MB) and x1s (N*64*4 = 25.6 MB) both alias bufA
    // (51.2 MB). Lifetimes: pairs dies at k_bincsr; x1s lives conv1-mm ->
    // conv2-gather; bufA first written by conv2-mm. No overlap.
    int2*  pairs = (int2*)bufA;
    float* x1s   = (float*)bufA;

    const int nblk = (N_ + THREADS - 1) / THREADS;
    const int gblk = ((size_t)N_ * 64 + THREADS - 1) / THREADS;     // wave/node

    // ---- zero accumulated buffers (fresh every call) ----
    hipMemsetAsync(sums, 0, (size_t)ngr * 64 * 4, stream);
    hipMemsetAsync(cnts, 0, (size_t)ngr * 4, stream);

    // ---- CSR build (atomic-free partition) ----
    k_partcnt<<<ablk, THREADS, (size_t)NB * 4, stream>>>(e_dst, counts, ablk, NB, E_);
    k_scanrows<<<NB, THREADS, 0, stream>>>(counts, bintot, ablk);
    k_binscan<<<1, 128, 0, stream>>>(bintot, binptr, NB, E_);
    k_partwrite<<<ablk, THREADS, (size_t)NB * 8, stream>>>(e_src, e_dst, binptr, counts, ablk, pairs, NB, E_);
    k_bincsr<<<NB, THREADS, 0, stream>>>(pairs, binptr, rowptr, dinv, srcs, N_, NB, E_);

    // ---- embeddings -> x [N,32] (pre-scaled by dinv) ----
    k_embed<6><<<((size_t)n_ev  * 32 + THREADS - 1) / THREADS, THREADS, 0, stream>>>(ev_f,  W_ev,  b_ev,  ev_i,  dinv, n_ev,  x);
    k_embed<4><<<((size_t)n_cs  * 32 + THREADS - 1) / THREADS, THREADS, 0, stream>>>(cs_f,  W_cs,  b_cs,  cs_i,  dinv, n_cs,  x);
    k_embed<2><<<((size_t)n_tr  * 32 + THREADS - 1) / THREADS, THREADS, 0, stream>>>(tr_f,  W_tr,  b_tr,  tr_i,  dinv, n_tr,  x);
    k_embed<5><<<((size_t)n_env * 32 + THREADS - 1) / THREADS, THREADS, 0, stream>>>(env_f, W_env, b_env, env_i, dinv, n_env, x);

    // ---- conv1: agg(x) @ W1 + b1 -> x1 ; also x1s = dinv*relu(x1) ----
    k_gather<32, false, false, false><<<gblk, THREADS, 0, stream>>>(
        x, rowptr, srcs, dinv, nullptr, nullptr, bufB, N_);
    k_mm<32, 64, true, false, 1><<<nblk, THREADS, 0, stream>>>(bufB, W1, b1, dinv, x1, x1s, N_);

    // ---- conv2: relu( agg(x1s) @ W2 + b2 ) -> bufA [N,128] ----
    k_gather<64, false, false, false><<<gblk, THREADS, 0, stream>>>(
        x1s, rowptr, srcs, dinv, nullptr, nullptr, bufB, N_);
    k_mm<64, 128, true, true, 0><<<nblk, THREADS, 0, stream>>>(bufB, W2, b2, nullptr, bufA, nullptr, N_);

    // ---- conv3: t3s = dinv*(bufA @ W3); h = relu(agg(t3s)+b3)+x1 -> bufA ----
    k_mm<128, 64, false, false, 2><<<nblk, THREADS, 0, stream>>>(bufA, W3, nullptr, dinv, bufB, nullptr, N_);
    k_gather<64, true, true, true><<<gblk, THREADS, 0, stream>>>(
        bufB, rowptr, srcs, dinv, b3, x1, bufA, N_);

    // ---- pool ----
    k_pool<<<nblk, THREADS, 0, stream>>>(bufA, batch, sums, cnts, N_);
    k_div<<<(out_size + THREADS - 1) / THREADS, THREADS, 0, stream>>>(sums, cnts, (float*)d_out, out_size);
}

// Round 5
// 599.328 us; speedup vs baseline: 2.3082x; 1.2392x over previous
//
#include <hip/hip_runtime.h>
#include <hip/hip_bf16.h>

// ---------------------------------------------------------------------------
// GNN Residual Feature Extractor
//   x = embed(type features)                       [N,32]
//   x1 = gcn(x, W1)+b1                             [N,64]
//   h  = relu(gcn(relu(x1),W2)+b2)                 [N,128]
//   h  = relu(gcn(h,W3)+b3) + x1                   [N,64]
//   out = segment_mean(h, batch)                   [100,64]
//
// gcn agg commutes with weight multiply; aggregate on narrow side.
// Tables are PRE-SCALED by dinv (and pre-activated) by their producers, so
// gathers are pure  out_i = dv_i * (t'_i + sum_s t'_s).
//
// CSR build: atomic-free two-pass radix partition (bin = dst>>10) — R4
// validated (CSR build dropped out of top-5).
//
// R5: k_mm rewritten (no LDS; W via wave-uniform scalar loads; col-split
// grid for occupancy — R4 showed 8.5% occupancy, 24% VALUBusy, 3.1M LDS
// conflicts). k_gather rewritten (float2 lanes, multi-edge wave groups,
// 8 edges in flight).
// ---------------------------------------------------------------------------

#define THREADS 256
#define BINSHIFT 10
#define EPBA 4096        // edges per partition block
#define SCANCH 8         // k_scanrows: values per thread (supports <=2048 blocks)

// ---------------- pass 1: per-(block,bin) exact counts ----------------
__global__ __launch_bounds__(THREADS)
void k_partcnt(const int* __restrict__ dst, int* __restrict__ counts,
               int nblk_part, int nb, int e) {
    extern __shared__ int h[];
    int t = threadIdx.x;
    for (int i = t; i < nb; i += THREADS) h[i] = 0;
    __syncthreads();
    int lo = blockIdx.x * EPBA;
    int hi = min(lo + EPBA, e);
    for (int i = lo + t; i < hi; i += THREADS)
        atomicAdd(&h[dst[i] >> BINSHIFT], 1);
    __syncthreads();
    for (int i = t; i < nb; i += THREADS)
        counts[(size_t)i * nblk_part + blockIdx.x] = h[i];
}

// ---------------- scan each bin's row of per-block counts ----------------
__global__ __launch_bounds__(THREADS)
void k_scanrows(int* __restrict__ counts, int* __restrict__ bintot, int nblk_part) {
    __shared__ int wsum[THREADS];
    int* row = counts + (size_t)blockIdx.x * nblk_part;
    int t = threadIdx.x;
    int base = t * SCANCH;
    int v[SCANCH];
    int s = 0;
#pragma unroll
    for (int k = 0; k < SCANCH; ++k) {
        v[k] = (base + k < nblk_part) ? row[base + k] : 0;
        s += v[k];
    }
    wsum[t] = s;
    __syncthreads();
    for (int off = 1; off < THREADS; off <<= 1) {
        int a = (t >= off) ? wsum[t - off] : 0;
        __syncthreads();
        wsum[t] += a;
        __syncthreads();
    }
    int run = wsum[t] - s;  // exclusive
#pragma unroll
    for (int k = 0; k < SCANCH; ++k) {
        int c = v[k];
        if (base + k < nblk_part) row[base + k] = run;
        run += c;
    }
    if (t == THREADS - 1) bintot[blockIdx.x] = run;
}

// ---------------- scan bin totals (single block, nb<=128) ----------------
__global__ __launch_bounds__(128)
void k_binscan(const int* __restrict__ bintot, int* __restrict__ binptr,
               int nb, int e) {
    __shared__ int lds[128];
    int t = threadIdx.x;
    int v = (t < nb) ? bintot[t] : 0;
    lds[t] = v;
    __syncthreads();
    for (int off = 1; off < 128; off <<= 1) {
        int a = (t >= off) ? lds[t - off] : 0;
        __syncthreads();
        lds[t] += a;
        __syncthreads();
    }
    if (t < nb) binptr[t] = lds[t] - v;  // exclusive
    if (t == 0) binptr[nb] = e;
}

// ---------------- pass 2: deterministic partition write ----------------
__global__ __launch_bounds__(THREADS)
void k_partwrite(const int* __restrict__ src, const int* __restrict__ dst,
                 const int* __restrict__ binptr, const int* __restrict__ counts,
                 int nblk_part, int2* __restrict__ pairs, int nb, int e) {
    extern __shared__ int smem[];
    int* base = smem;       // nb
    int* cnt  = smem + nb;  // nb
    int t = threadIdx.x;
    for (int i = t; i < nb; i += THREADS) {
        base[i] = binptr[i] + counts[(size_t)i * nblk_part + blockIdx.x];
        cnt[i] = 0;
    }
    __syncthreads();
    int lo = blockIdx.x * EPBA;
    int hi = min(lo + EPBA, e);
    for (int i = lo + t; i < hi; i += THREADS) {
        int s = src[i], d = dst[i];
        int b = d >> BINSHIFT;
        int pos = atomicAdd(&cnt[b], 1);   // LDS only
        pairs[base[b] + pos] = make_int2(s, d);
    }
}

// ---------------- per-bin CSR finalize ----------------
__global__ __launch_bounds__(THREADS)
void k_bincsr(const int2* __restrict__ pairs, const int* __restrict__ binptr,
              int* __restrict__ rowptr, float* __restrict__ dinv,
              int* __restrict__ srcs, int n, int nb, int e) {
    __shared__ int lcnt[1024];
    __shared__ int lofs[1024];
    __shared__ int wsum[THREADS];
    int b = blockIdx.x, t = threadIdx.x;
    int e0 = binptr[b], e1 = binptr[b + 1];
    int n0 = b << BINSHIFT;
    for (int i = t; i < 1024; i += THREADS) lcnt[i] = 0;
    __syncthreads();
    for (int j = e0 + t; j < e1; j += THREADS)
        atomicAdd(&lcnt[pairs[j].y - n0], 1);
    __syncthreads();
    int c0 = lcnt[4 * t + 0], c1 = lcnt[4 * t + 1];
    int c2 = lcnt[4 * t + 2], c3 = lcnt[4 * t + 3];
    int s = c0 + c1 + c2 + c3;
    wsum[t] = s;
    __syncthreads();
    for (int off = 1; off < THREADS; off <<= 1) {
        int a = (t >= off) ? wsum[t - off] : 0;
        __syncthreads();
        wsum[t] += a;
        __syncthreads();
    }
    int excl = wsum[t] - s;
    lofs[4 * t + 0] = excl;
    lofs[4 * t + 1] = excl + c0;
    lofs[4 * t + 2] = excl + c0 + c1;
    lofs[4 * t + 3] = excl + c0 + c1 + c2;
    __syncthreads();
    for (int i = t; i < 1024; i += THREADS) {
        int node = n0 + i;
        if (node < n) {
            rowptr[node] = e0 + lofs[i];
            dinv[node] = rsqrtf((float)lcnt[i] + 1.0f);
        }
    }
    if (b == nb - 1 && t == 0) rowptr[n] = e;
    __syncthreads();
    for (int j = e0 + t; j < e1; j += THREADS) {
        int2 p = pairs[j];
        int pos = e0 + atomicAdd(&lofs[p.y - n0], 1);
        srcs[pos] = p.x;
    }
}

// ---------------- embedding: x[idx[r]] = dinv * (f[r] @ W + b) ----------------
template <int K>
__global__ __launch_bounds__(THREADS)
void k_embed(const float* __restrict__ f, const float* __restrict__ W,
             const float* __restrict__ b, const int* __restrict__ idx,
             const float* __restrict__ dinv, int rows, float* __restrict__ x) {
    int g = blockIdx.x * THREADS + threadIdx.x;
    int r = g >> 5, c = g & 31;
    if (r >= rows) return;
    int node = idx[r];
    float a = b[c];
#pragma unroll
    for (int k = 0; k < K; ++k) a += f[r * K + k] * W[k * 32 + c];
    x[(size_t)node * 32 + c] = dinv[node] * a;
}

// ---------------- gather aggregation (tables pre-scaled by dinv) ----------------
// out[i] = dv_i * (tbl[i] + sum_s tbl[s])  [+bias][relu][+resid]
// float2 per lane; wave sub-groups process different edges whose indices are
// wave-uniform scalar loads; shfl-combine at the end.
template <int C, bool HASBIAS, bool OUTRELU, bool HASRES>
__global__ __launch_bounds__(THREADS)
void k_gather(const float* __restrict__ tbl, const int* __restrict__ rowptr,
              const int* __restrict__ srcs, const float* __restrict__ dinv,
              const float* __restrict__ bias, const float* __restrict__ resid,
              float* __restrict__ out, int n) {
    int gt = blockIdx.x * THREADS + threadIdx.x;
    int node = gt >> 6;
    int lane = threadIdx.x & 63;
    if (node >= n) return;
    float dv = dinv[node];
    int beg = rowptr[node], end = rowptr[node + 1];
    const float2* t2 = reinterpret_cast<const float2*>(tbl);

    if (C == 64) {
        int col = lane & 31, half = lane >> 5;   // 2 halves x 32 float2 lanes
        float ax = 0.f, ay = 0.f;
        int j = beg;
        for (; j + 8 <= end; j += 8) {
            int s0 = srcs[j + 0], s1 = srcs[j + 1], s2 = srcs[j + 2], s3 = srcs[j + 3];
            int s4 = srcs[j + 4], s5 = srcs[j + 5], s6 = srcs[j + 6], s7 = srcs[j + 7];
            float2 v0 = t2[(size_t)(half ? s1 : s0) * 32 + col];
            float2 v1 = t2[(size_t)(half ? s3 : s2) * 32 + col];
            float2 v2 = t2[(size_t)(half ? s5 : s4) * 32 + col];
            float2 v3 = t2[(size_t)(half ? s7 : s6) * 32 + col];
            ax += v0.x + v1.x + v2.x + v3.x;
            ay += v0.y + v1.y + v2.y + v3.y;
        }
        for (; j + 2 <= end; j += 2) {
            int s0 = srcs[j], s1 = srcs[j + 1];
            float2 v = t2[(size_t)(half ? s1 : s0) * 32 + col];
            ax += v.x; ay += v.y;
        }
        if (j < end && half == 0) {
            float2 v = t2[(size_t)srcs[j] * 32 + col];
            ax += v.x; ay += v.y;
        }
        ax += __shfl_down(ax, 32, 64);
        ay += __shfl_down(ay, 32, 64);
        if (half == 0) {
            float2 self = t2[(size_t)node * 32 + col];
            float rx = dv * (ax + self.x);
            float ry = dv * (ay + self.y);
            if (HASBIAS) { rx += bias[2 * col]; ry += bias[2 * col + 1]; }
            if (OUTRELU) { rx = fmaxf(rx, 0.f); ry = fmaxf(ry, 0.f); }
            if (HASRES) {
                float2 rr = reinterpret_cast<const float2*>(resid)[(size_t)node * 32 + col];
                rx += rr.x; ry += rr.y;
            }
            float2 o = {rx, ry};
            reinterpret_cast<float2*>(out)[(size_t)node * 32 + col] = o;
        }
    } else {  // C == 32: 4 quarter-groups x 16 float2 lanes
        int col = lane & 15, qw = lane >> 4;
        float ax = 0.f, ay = 0.f;
        int j = beg;
        for (; j + 8 <= end; j += 8) {
            int s0 = srcs[j + 0], s1 = srcs[j + 1], s2 = srcs[j + 2], s3 = srcs[j + 3];
            int s4 = srcs[j + 4], s5 = srcs[j + 5], s6 = srcs[j + 6], s7 = srcs[j + 7];
            int sa = (qw & 1) ? s1 : s0, sb = (qw & 1) ? s3 : s2;
            int se0 = (qw & 2) ? sb : sa;
            int sc = (qw & 1) ? s5 : s4, sd = (qw & 1) ? s7 : s6;
            int se1 = (qw & 2) ? sd : sc;
            float2 v0 = t2[(size_t)se0 * 16 + col];
            float2 v1 = t2[(size_t)se1 * 16 + col];
            ax += v0.x + v1.x; ay += v0.y + v1.y;
        }
        for (; j + 4 <= end; j += 4) {
            int s0 = srcs[j + 0], s1 = srcs[j + 1], s2 = srcs[j + 2], s3 = srcs[j + 3];
            int sa = (qw & 1) ? s1 : s0, sb = (qw & 1) ? s3 : s2;
            int se = (qw & 2) ? sb : sa;
            float2 v = t2[(size_t)se * 16 + col];
            ax += v.x; ay += v.y;
        }
        int rem = end - j;
        if (qw < rem) {
            float2 v = t2[(size_t)srcs[j + qw] * 16 + col];
            ax += v.x; ay += v.y;
        }
        ax += __shfl_down(ax, 32, 64);
        ay += __shfl_down(ay, 32, 64);
        ax += __shfl_down(ax, 16, 64);
        ay += __shfl_down(ay, 16, 64);
        if (lane < 16) {
            float2 self = t2[(size_t)node * 16 + col];
            float rx = dv * (ax + self.x);
            float ry = dv * (ay + self.y);
            float2 o = {rx, ry};
            reinterpret_cast<float2*>(out)[(size_t)node * 16 + col] = o;
        }
    }
}

// ---------------- dense matmul: out[N,FOUT] = in[N,FIN] @ W + b ----------------
// Row-per-thread; row cached in registers (static unroll); W and bias read as
// wave-uniform scalar loads (no LDS, no barrier). Grid.y splits columns
// (CPB cols per block) for occupancy.
// EXTRA: 0 = plain; 1 = also write out2 = dinv*relu(out); 2 = out scaled by dinv.
template <int FIN, int FOUT, int CPB, bool HASBIAS, bool OUTRELU, int EXTRA>
__global__ __launch_bounds__(THREADS)
void k_mm(const float* __restrict__ xin, const float* __restrict__ W,
          const float* __restrict__ bias, const float* __restrict__ dinv,
          float* __restrict__ out, float* __restrict__ out2, int nrows) {
    int row = blockIdx.x * THREADS + threadIdx.x;
    if (row >= nrows) return;
    int cbase = blockIdx.y * CPB;

    float xrow[FIN];
    const float4* xr4 = reinterpret_cast<const float4*>(xin + (size_t)row * FIN);
#pragma unroll
    for (int q = 0; q < FIN / 4; ++q) {
        float4 v = xr4[q];
        xrow[4 * q + 0] = v.x; xrow[4 * q + 1] = v.y;
        xrow[4 * q + 2] = v.z; xrow[4 * q + 3] = v.w;
    }
    float dv = (EXTRA != 0) ? dinv[row] : 0.f;

#pragma unroll 1
    for (int cc = 0; cc < CPB; cc += 8) {
        int c0 = cbase + cc;
        float a[8];
#pragma unroll
        for (int i = 0; i < 8; ++i) a[i] = HASBIAS ? bias[c0 + i] : 0.f;
#pragma unroll
        for (int k = 0; k < FIN; ++k) {
            float xk = xrow[k];
            const float* wr = W + (size_t)k * FOUT + c0;
#pragma unroll
            for (int i = 0; i < 8; ++i) a[i] = fmaf(xk, wr[i], a[i]);
        }
#pragma unroll
        for (int i = 0; i < 8; ++i) {
            if (OUTRELU) a[i] = fmaxf(a[i], 0.f);
            if (EXTRA == 2) a[i] *= dv;
        }
        float4 o0 = {a[0], a[1], a[2], a[3]};
        float4 o1 = {a[4], a[5], a[6], a[7]};
        float4* op = reinterpret_cast<float4*>(out + (size_t)row * FOUT + c0);
        op[0] = o0; op[1] = o1;
        if (EXTRA == 1) {
            float4 p0 = {dv * fmaxf(a[0], 0.f), dv * fmaxf(a[1], 0.f),
                         dv * fmaxf(a[2], 0.f), dv * fmaxf(a[3], 0.f)};
            float4 p1 = {dv * fmaxf(a[4], 0.f), dv * fmaxf(a[5], 0.f),
                         dv * fmaxf(a[6], 0.f), dv * fmaxf(a[7], 0.f)};
            float4* o2p = reinterpret_cast<float4*>(out2 + (size_t)row * FOUT + c0);
            o2p[0] = p0; o2p[1] = p1;
        }
    }
}

// ---------------- segment mean pool ----------------
__global__ __launch_bounds__(THREADS)
void k_pool(const float* __restrict__ h, const int* __restrict__ batch,
            float* __restrict__ sums, float* __restrict__ cnts, int n) {
    int c = threadIdx.x & 63;
    int rq = threadIdx.x >> 6;  // 0..3
    int r0 = blockIdx.x * THREADS;
    int rend = min(r0 + THREADS, n);
    int curg = -1;
    float acc = 0.f, cacc = 0.f;
    for (int r = r0 + rq; r < rend; r += 4) {
        int g = batch[r];
        if (g != curg) {
            if (curg >= 0) {
                atomicAdd(&sums[(size_t)curg * 64 + c], acc);
                if (c == 0) atomicAdd(&cnts[curg], cacc);
            }
            curg = g; acc = 0.f; cacc = 0.f;
        }
        acc += h[(size_t)r * 64 + c];
        cacc += 1.f;
    }
    if (curg >= 0) {
        atomicAdd(&sums[(size_t)curg * 64 + c], acc);
        if (c == 0) atomicAdd(&cnts[curg], cacc);
    }
}

__global__ __launch_bounds__(THREADS)
void k_div(const float* __restrict__ sums, const float* __restrict__ cnts,
           float* __restrict__ out, int total) {
    int i = blockIdx.x * THREADS + threadIdx.x;
    if (i < total) out[i] = sums[i] / cnts[i >> 6];
}

// ---------------------------------------------------------------------------
static inline size_t alignup(size_t v) { return (v + 255) & ~(size_t)255; }

extern "C" void kernel_launch(void* const* d_in, const int* in_sizes, int n_in,
                              void* d_out, int out_size, void* d_ws, size_t ws_size,
                              hipStream_t stream) {
    const float* ev_f  = (const float*)d_in[0];
    const float* cs_f  = (const float*)d_in[1];
    const float* tr_f  = (const float*)d_in[2];
    const float* env_f = (const float*)d_in[3];
    const int*   ei    = (const int*)d_in[4];
    const int*   ev_i  = (const int*)d_in[5];
    const int*   cs_i  = (const int*)d_in[6];
    const int*   tr_i  = (const int*)d_in[7];
    const int*   env_i = (const int*)d_in[8];
    const int*   batch = (const int*)d_in[9];
    const float* W_ev = (const float*)d_in[10]; const float* b_ev = (const float*)d_in[11];
    const float* W_cs = (const float*)d_in[12]; const float* b_cs = (const float*)d_in[13];
    const float* W_tr = (const float*)d_in[14]; const float* b_tr = (const float*)d_in[15];
    const float* W_env= (const float*)d_in[16]; const float* b_env= (const float*)d_in[17];
    const float* W1 = (const float*)d_in[18]; const float* b1 = (const float*)d_in[19];
    const float* W2 = (const float*)d_in[20]; const float* b2 = (const float*)d_in[21];
    const float* W3 = (const float*)d_in[22]; const float* b3 = (const float*)d_in[23];

    const int E_ = in_sizes[4] / 2;
    const int N_ = in_sizes[9];
    const int n_ev  = in_sizes[5];
    const int n_cs  = in_sizes[6];
    const int n_tr  = in_sizes[7];
    const int n_env = in_sizes[8];
    const int ngr   = out_size / 64;  // 100 graphs

    const int* e_src = ei;
    const int* e_dst = ei + E_;

    const int NB   = (N_ + (1 << BINSHIFT) - 1) >> BINSHIFT;  // 98 bins
    const int ablk = (E_ + EPBA - 1) / EPBA;                  // 782 partition blocks

    // ---- workspace carve-up ----
    char* p = (char*)d_ws;
    int*   counts = (int*)p;    p += alignup((size_t)NB * ablk * 4);
    int*   bintot = (int*)p;    p += alignup((size_t)NB * 4);
    int*   binptr = (int*)p;    p += alignup(((size_t)NB + 1) * 4);
    int*   rowptr = (int*)p;    p += alignup(((size_t)N_ + 1) * 4);
    float* dinv   = (float*)p;  p += alignup((size_t)N_ * 4);
    int*   srcs   = (int*)p;    p += alignup((size_t)E_ * 4);
    float* x      = (float*)p;  p += alignup((size_t)N_ * 32 * 4);
    float* x1     = (float*)p;  p += alignup((size_t)N_ * 64 * 4);
    float* bufB   = (float*)p;  p += alignup((size_t)N_ * 64 * 4);
    float* bufA   = (float*)p;  p += alignup((size_t)N_ * 128 * 4);
    float* sums   = (float*)p;  p += alignup((size_t)ngr * 64 * 4);
    float* cnts   = (float*)p;  p += alignup((size_t)ngr * 4);

    // pairs (E int2 = 25.6 MB) and x1s (N*64*4 = 25.6 MB) both alias bufA
    // (51.2 MB). Lifetimes: pairs dies at k_bincsr; x1s lives conv1-mm ->
    // conv2-gather; bufA first written by conv2-mm. No overlap.
    int2*  pairs = (int2*)bufA;
    float* x1s   = (float*)bufA;

    const int nblk = (N_ + THREADS - 1) / THREADS;
    const int gblk = ((size_t)N_ * 64 + THREADS - 1) / THREADS;     // wave/node

    // ---- zero accumulated buffers (fresh every call) ----
    hipMemsetAsync(sums, 0, (size_t)ngr * 64 * 4, stream);
    hipMemsetAsync(cnts, 0, (size_t)ngr * 4, stream);

    // ---- CSR build (atomic-free partition) ----
    k_partcnt<<<ablk, THREADS, (size_t)NB * 4, stream>>>(e_dst, counts, ablk, NB, E_);
    k_scanrows<<<NB, THREADS, 0, stream>>>(counts, bintot, ablk);
    k_binscan<<<1, 128, 0, stream>>>(bintot, binptr, NB, E_);
    k_partwrite<<<ablk, THREADS, (size_t)NB * 8, stream>>>(e_src, e_dst, binptr, counts, ablk, pairs, NB, E_);
    k_bincsr<<<NB, THREADS, 0, stream>>>(pairs, binptr, rowptr, dinv, srcs, N_, NB, E_);

    // ---- embeddings -> x [N,32] (pre-scaled by dinv) ----
    k_embed<6><<<((size_t)n_ev  * 32 + THREADS - 1) / THREADS, THREADS, 0, stream>>>(ev_f,  W_ev,  b_ev,  ev_i,  dinv, n_ev,  x);
    k_embed<4><<<((size_t)n_cs  * 32 + THREADS - 1) / THREADS, THREADS, 0, stream>>>(cs_f,  W_cs,  b_cs,  cs_i,  dinv, n_cs,  x);
    k_embed<2><<<((size_t)n_tr  * 32 + THREADS - 1) / THREADS, THREADS, 0, stream>>>(tr_f,  W_tr,  b_tr,  tr_i,  dinv, n_tr,  x);
    k_embed<5><<<((size_t)n_env * 32 + THREADS - 1) / THREADS, THREADS, 0, stream>>>(env_f, W_env, b_env, env_i, dinv, n_env, x);

    // ---- conv1: agg(x) @ W1 + b1 -> x1 ; also x1s = dinv*relu(x1) ----
    k_gather<32, false, false, false><<<gblk, THREADS, 0, stream>>>(
        x, rowptr, srcs, dinv, nullptr, nullptr, bufB, N_);
    k_mm<32, 64, 16, true, false, 1><<<dim3(nblk, 4), THREADS, 0, stream>>>(
        bufB, W1, b1, dinv, x1, x1s, N_);

    // ---- conv2: relu( agg(x1s) @ W2 + b2 ) -> bufA [N,128] ----
    k_gather<64, false, false, false><<<gblk, THREADS, 0, stream>>>(
        x1s, rowptr, srcs, dinv, nullptr, nullptr, bufB, N_);
    k_mm<64, 128, 32, true, true, 0><<<dim3(nblk, 4), THREADS, 0, stream>>>(
        bufB, W2, b2, nullptr, bufA, nullptr, N_);

    // ---- conv3: t3s = dinv*(bufA @ W3); h = relu(agg(t3s)+b3)+x1 -> bufA ----
    k_mm<128, 64, 32, false, false, 2><<<dim3(nblk, 2), THREADS, 0, stream>>>(
        bufA, W3, nullptr, dinv, bufB, nullptr, N_);
    k_gather<64, true, true, true><<<gblk, THREADS, 0, stream>>>(
        bufB, rowptr, srcs, dinv, b3, x1, bufA, N_);

    // ---- pool ----
    k_pool<<<nblk, THREADS, 0, stream>>>(bufA, batch, sums, cnts, N_);
    k_div<<<(out_size + THREADS - 1) / THREADS, THREADS, 0, stream>>>(sums, cnts, (float*)d_out, out_size);
}

// Round 6
// 495.312 us; speedup vs baseline: 2.7929x; 1.2100x over previous
//
#include <hip/hip_runtime.h>
#include <hip/hip_bf16.h>

// ---------------------------------------------------------------------------
// GNN Residual Feature Extractor
//   x = embed(type features)                       [N,32]
//   x1 = gcn(x, W1)+b1                             [N,64]
//   h  = relu(gcn(relu(x1),W2)+b2)                 [N,128]
//   h  = relu(gcn(h,W3)+b3) + x1                   [N,64]
//   out = segment_mean(h, batch)                   [100,64]
//
// gcn agg commutes with weight multiply; aggregate on narrow side.
// Gather TABLES are bf16 (packed u32 pairs), PRE-SCALED by dinv and
// pre-activated by their producers; accumulation stays f32. Halves the
// random-row gather traffic (R5: 376 MB FETCH/dispatch, transaction-bound).
//
// CSR build: atomic-free two-pass radix partition (bin = dst>>10) — R4/R5
// validated.
// ---------------------------------------------------------------------------

#define THREADS 256
#define BINSHIFT 10
#define EPBA 4096        // edges per partition block
#define SCANCH 8         // k_scanrows: values per thread (supports <=2048 blocks)

// ---------------- bf16 helpers ----------------
__device__ __forceinline__ unsigned bfpack2(float lo, float hi) {
    unsigned ul = __float_as_uint(lo);
    unsigned uh = __float_as_uint(hi);
    ul = (ul + 0x7fffu + ((ul >> 16) & 1u)) >> 16;          // rne, low half
    uh = (uh + 0x7fffu + ((uh >> 16) & 1u)) & 0xffff0000u;  // rne, high half
    return ul | uh;
}

__device__ __forceinline__ void bfacc(uint2 v, float& a0, float& a1,
                                      float& a2, float& a3) {
    a0 += __uint_as_float(v.x << 16);
    a1 += __uint_as_float(v.x & 0xffff0000u);
    a2 += __uint_as_float(v.y << 16);
    a3 += __uint_as_float(v.y & 0xffff0000u);
}

// ---------------- pass 1: per-(block,bin) exact counts ----------------
__global__ __launch_bounds__(THREADS)
void k_partcnt(const int* __restrict__ dst, int* __restrict__ counts,
               int nblk_part, int nb, int e) {
    extern __shared__ int h[];
    int t = threadIdx.x;
    for (int i = t; i < nb; i += THREADS) h[i] = 0;
    __syncthreads();
    int lo = blockIdx.x * EPBA;
    int hi = min(lo + EPBA, e);
    for (int i = lo + t; i < hi; i += THREADS)
        atomicAdd(&h[dst[i] >> BINSHIFT], 1);
    __syncthreads();
    for (int i = t; i < nb; i += THREADS)
        counts[(size_t)i * nblk_part + blockIdx.x] = h[i];
}

// ---------------- scan each bin's row of per-block counts ----------------
__global__ __launch_bounds__(THREADS)
void k_scanrows(int* __restrict__ counts, int* __restrict__ bintot, int nblk_part) {
    __shared__ int wsum[THREADS];
    int* row = counts + (size_t)blockIdx.x * nblk_part;
    int t = threadIdx.x;
    int base = t * SCANCH;
    int v[SCANCH];
    int s = 0;
#pragma unroll
    for (int k = 0; k < SCANCH; ++k) {
        v[k] = (base + k < nblk_part) ? row[base + k] : 0;
        s += v[k];
    }
    wsum[t] = s;
    __syncthreads();
    for (int off = 1; off < THREADS; off <<= 1) {
        int a = (t >= off) ? wsum[t - off] : 0;
        __syncthreads();
        wsum[t] += a;
        __syncthreads();
    }
    int run = wsum[t] - s;  // exclusive
#pragma unroll
    for (int k = 0; k < SCANCH; ++k) {
        int c = v[k];
        if (base + k < nblk_part) row[base + k] = run;
        run += c;
    }
    if (t == THREADS - 1) bintot[blockIdx.x] = run;
}

// ---------------- scan bin totals (single block, nb<=128) ----------------
__global__ __launch_bounds__(128)
void k_binscan(const int* __restrict__ bintot, int* __restrict__ binptr,
               int nb, int e) {
    __shared__ int lds[128];
    int t = threadIdx.x;
    int v = (t < nb) ? bintot[t] : 0;
    lds[t] = v;
    __syncthreads();
    for (int off = 1; off < 128; off <<= 1) {
        int a = (t >= off) ? lds[t - off] : 0;
        __syncthreads();
        lds[t] += a;
        __syncthreads();
    }
    if (t < nb) binptr[t] = lds[t] - v;  // exclusive
    if (t == 0) binptr[nb] = e;
}

// ---------------- pass 2: deterministic partition write ----------------
__global__ __launch_bounds__(THREADS)
void k_partwrite(const int* __restrict__ src, const int* __restrict__ dst,
                 const int* __restrict__ binptr, const int* __restrict__ counts,
                 int nblk_part, int2* __restrict__ pairs, int nb, int e) {
    extern __shared__ int smem[];
    int* base = smem;       // nb
    int* cnt  = smem + nb;  // nb
    int t = threadIdx.x;
    for (int i = t; i < nb; i += THREADS) {
        base[i] = binptr[i] + counts[(size_t)i * nblk_part + blockIdx.x];
        cnt[i] = 0;
    }
    __syncthreads();
    int lo = blockIdx.x * EPBA;
    int hi = min(lo + EPBA, e);
    for (int i = lo + t; i < hi; i += THREADS) {
        int s = src[i], d = dst[i];
        int b = d >> BINSHIFT;
        int pos = atomicAdd(&cnt[b], 1);   // LDS only
        pairs[base[b] + pos] = make_int2(s, d);
    }
}

// ---------------- per-bin CSR finalize ----------------
__global__ __launch_bounds__(THREADS)
void k_bincsr(const int2* __restrict__ pairs, const int* __restrict__ binptr,
              int* __restrict__ rowptr, float* __restrict__ dinv,
              int* __restrict__ srcs, int n, int nb, int e) {
    __shared__ int lcnt[1024];
    __shared__ int lofs[1024];
    __shared__ int wsum[THREADS];
    int b = blockIdx.x, t = threadIdx.x;
    int e0 = binptr[b], e1 = binptr[b + 1];
    int n0 = b << BINSHIFT;
    for (int i = t; i < 1024; i += THREADS) lcnt[i] = 0;
    __syncthreads();
    for (int j = e0 + t; j < e1; j += THREADS)
        atomicAdd(&lcnt[pairs[j].y - n0], 1);
    __syncthreads();
    int c0 = lcnt[4 * t + 0], c1 = lcnt[4 * t + 1];
    int c2 = lcnt[4 * t + 2], c3 = lcnt[4 * t + 3];
    int s = c0 + c1 + c2 + c3;
    wsum[t] = s;
    __syncthreads();
    for (int off = 1; off < THREADS; off <<= 1) {
        int a = (t >= off) ? wsum[t - off] : 0;
        __syncthreads();
        wsum[t] += a;
        __syncthreads();
    }
    int excl = wsum[t] - s;
    lofs[4 * t + 0] = excl;
    lofs[4 * t + 1] = excl + c0;
    lofs[4 * t + 2] = excl + c0 + c1;
    lofs[4 * t + 3] = excl + c0 + c1 + c2;
    __syncthreads();
    for (int i = t; i < 1024; i += THREADS) {
        int node = n0 + i;
        if (node < n) {
            rowptr[node] = e0 + lofs[i];
            dinv[node] = rsqrtf((float)lcnt[i] + 1.0f);
        }
    }
    if (b == nb - 1 && t == 0) rowptr[n] = e;
    __syncthreads();
    for (int j = e0 + t; j < e1; j += THREADS) {
        int2 p = pairs[j];
        int pos = e0 + atomicAdd(&lofs[p.y - n0], 1);
        srcs[pos] = p.x;
    }
}

// ---------------- embedding: xb[idx[r]] = bf16(dinv * (f[r] @ W + b)) --------
// thread handles 2 adjacent cols -> one packed u32 write.
template <int K>
__global__ __launch_bounds__(THREADS)
void k_embed(const float* __restrict__ f, const float* __restrict__ W,
             const float* __restrict__ b, const int* __restrict__ idx,
             const float* __restrict__ dinv, int rows, unsigned* __restrict__ xb) {
    int g = blockIdx.x * THREADS + threadIdx.x;
    int r = g >> 4, cp = g & 15;
    if (r >= rows) return;
    int node = idx[r];
    float dv = dinv[node];
    float a0 = b[2 * cp], a1 = b[2 * cp + 1];
#pragma unroll
    for (int k = 0; k < K; ++k) {
        float fv = f[r * K + k];
        a0 += fv * W[k * 32 + 2 * cp];
        a1 += fv * W[k * 32 + 2 * cp + 1];
    }
    xb[(size_t)node * 16 + cp] = bfpack2(dv * a0, dv * a1);
}

// ---------------- gather (bf16 table, row=128B): one wave per node ----------
// 4 quarter-groups of 16 lanes; each quarter owns one edge's full row.
// out[i] = dv_i * (tbl[i] + sum_s tbl[s])  [+bias][relu][+resid], f32 out.
template <bool HASBIAS, bool OUTRELU, bool HASRES>
__global__ __launch_bounds__(THREADS)
void k_gather64(const unsigned* __restrict__ tblb, const int* __restrict__ rowptr,
                const int* __restrict__ srcs, const float* __restrict__ dinv,
                const float* __restrict__ bias, const float* __restrict__ resid,
                float* __restrict__ out, int n) {
    int gt = blockIdx.x * THREADS + threadIdx.x;
    int node = gt >> 6;
    int lane = threadIdx.x & 63;
    if (node >= n) return;
    int qw = lane >> 4, li = lane & 15;
    const uint2* t2 = reinterpret_cast<const uint2*>(tblb);
    float a0 = 0.f, a1 = 0.f, a2 = 0.f, a3 = 0.f;
    int beg = rowptr[node], end = rowptr[node + 1];
    int j = beg;
    for (; j + 16 <= end; j += 16) {          // 16 edges, 4 rows in flight
        int i0 = srcs[j + qw];
        int i1 = srcs[j + 4 + qw];
        int i2 = srcs[j + 8 + qw];
        int i3 = srcs[j + 12 + qw];
        uint2 v0 = t2[(size_t)i0 * 16 + li];
        uint2 v1 = t2[(size_t)i1 * 16 + li];
        uint2 v2 = t2[(size_t)i2 * 16 + li];
        uint2 v3 = t2[(size_t)i3 * 16 + li];
        bfacc(v0, a0, a1, a2, a3);
        bfacc(v1, a0, a1, a2, a3);
        bfacc(v2, a0, a1, a2, a3);
        bfacc(v3, a0, a1, a2, a3);
    }
    for (; j + 8 <= end; j += 8) {
        int i0 = srcs[j + qw];
        int i1 = srcs[j + 4 + qw];
        uint2 v0 = t2[(size_t)i0 * 16 + li];
        uint2 v1 = t2[(size_t)i1 * 16 + li];
        bfacc(v0, a0, a1, a2, a3);
        bfacc(v1, a0, a1, a2, a3);
    }
    int rem = end - j;
    if (qw < rem) {
        uint2 v = t2[(size_t)srcs[j + qw] * 16 + li];
        bfacc(v, a0, a1, a2, a3);
    }
    if (qw + 4 < rem) {
        uint2 v = t2[(size_t)srcs[j + 4 + qw] * 16 + li];
        bfacc(v, a0, a1, a2, a3);
    }
    a0 += __shfl_down(a0, 32, 64); a1 += __shfl_down(a1, 32, 64);
    a2 += __shfl_down(a2, 32, 64); a3 += __shfl_down(a3, 32, 64);
    a0 += __shfl_down(a0, 16, 64); a1 += __shfl_down(a1, 16, 64);
    a2 += __shfl_down(a2, 16, 64); a3 += __shfl_down(a3, 16, 64);
    if (lane < 16) {
        uint2 sv = t2[(size_t)node * 16 + li];
        bfacc(sv, a0, a1, a2, a3);
        float dv = dinv[node];
        float r0 = dv * a0, r1 = dv * a1, r2 = dv * a2, r3 = dv * a3;
        if (HASBIAS) {
            float4 bv = *reinterpret_cast<const float4*>(bias + 4 * li);
            r0 += bv.x; r1 += bv.y; r2 += bv.z; r3 += bv.w;
        }
        if (OUTRELU) {
            r0 = fmaxf(r0, 0.f); r1 = fmaxf(r1, 0.f);
            r2 = fmaxf(r2, 0.f); r3 = fmaxf(r3, 0.f);
        }
        if (HASRES) {
            float4 rv = reinterpret_cast<const float4*>(resid)[(size_t)node * 16 + li];
            r0 += rv.x; r1 += rv.y; r2 += rv.z; r3 += rv.w;
        }
        float4 o = {r0, r1, r2, r3};
        reinterpret_cast<float4*>(out)[(size_t)node * 16 + li] = o;
    }
}

// ---------------- gather (bf16 table, row=64B): 8 groups of 8 lanes ---------
__global__ __launch_bounds__(THREADS)
void k_gather32(const unsigned* __restrict__ tblb, const int* __restrict__ rowptr,
                const int* __restrict__ srcs, const float* __restrict__ dinv,
                float* __restrict__ out, int n) {
    int gt = blockIdx.x * THREADS + threadIdx.x;
    int node = gt >> 6;
    int lane = threadIdx.x & 63;
    if (node >= n) return;
    int og = lane >> 3, li = lane & 7;
    const uint2* t2 = reinterpret_cast<const uint2*>(tblb);
    float a0 = 0.f, a1 = 0.f, a2 = 0.f, a3 = 0.f;
    int beg = rowptr[node], end = rowptr[node + 1];
    int j = beg;
    for (; j + 16 <= end; j += 16) {          // 16 edges, 2 rows in flight/lane
        int i0 = srcs[j + og];
        int i1 = srcs[j + 8 + og];
        uint2 v0 = t2[(size_t)i0 * 8 + li];
        uint2 v1 = t2[(size_t)i1 * 8 + li];
        bfacc(v0, a0, a1, a2, a3);
        bfacc(v1, a0, a1, a2, a3);
    }
    for (; j + 8 <= end; j += 8) {
        int i0 = srcs[j + og];
        uint2 v0 = t2[(size_t)i0 * 8 + li];
        bfacc(v0, a0, a1, a2, a3);
    }
    int rem = end - j;
    if (og < rem) {
        uint2 v = t2[(size_t)srcs[j + og] * 8 + li];
        bfacc(v, a0, a1, a2, a3);
    }
    a0 += __shfl_down(a0, 32, 64); a1 += __shfl_down(a1, 32, 64);
    a2 += __shfl_down(a2, 32, 64); a3 += __shfl_down(a3, 32, 64);
    a0 += __shfl_down(a0, 16, 64); a1 += __shfl_down(a1, 16, 64);
    a2 += __shfl_down(a2, 16, 64); a3 += __shfl_down(a3, 16, 64);
    a0 += __shfl_down(a0, 8, 64);  a1 += __shfl_down(a1, 8, 64);
    a2 += __shfl_down(a2, 8, 64);  a3 += __shfl_down(a3, 8, 64);
    if (lane < 8) {
        uint2 sv = t2[(size_t)node * 8 + li];
        bfacc(sv, a0, a1, a2, a3);
        float dv = dinv[node];
        float4 o = {dv * a0, dv * a1, dv * a2, dv * a3};
        reinterpret_cast<float4*>(out)[(size_t)node * 8 + li] = o;
    }
}

// ---------------- dense matmul: out[N,FOUT] = in[N,FIN] @ W + b ----------------
// Row-per-thread; row in registers; W/bias via wave-uniform scalar loads.
// Grid.y splits columns (CPB per block).
// EXTRA: 0 = f32 out only; 1 = f32 out AND out2b = bf16(dinv*relu(out));
//        2 = out2b = bf16(dinv*out) only (no f32 write).
template <int FIN, int FOUT, int CPB, bool HASBIAS, bool OUTRELU, int EXTRA>
__global__ __launch_bounds__(THREADS)
void k_mm(const float* __restrict__ xin, const float* __restrict__ W,
          const float* __restrict__ bias, const float* __restrict__ dinv,
          float* __restrict__ out, unsigned* __restrict__ out2b, int nrows) {
    int row = blockIdx.x * THREADS + threadIdx.x;
    if (row >= nrows) return;
    int cbase = blockIdx.y * CPB;

    float xrow[FIN];
    const float4* xr4 = reinterpret_cast<const float4*>(xin + (size_t)row * FIN);
#pragma unroll
    for (int q = 0; q < FIN / 4; ++q) {
        float4 v = xr4[q];
        xrow[4 * q + 0] = v.x; xrow[4 * q + 1] = v.y;
        xrow[4 * q + 2] = v.z; xrow[4 * q + 3] = v.w;
    }
    float dv = (EXTRA != 0) ? dinv[row] : 0.f;

#pragma unroll 1
    for (int cc = 0; cc < CPB; cc += 8) {
        int c0 = cbase + cc;
        float a[8];
#pragma unroll
        for (int i = 0; i < 8; ++i) a[i] = HASBIAS ? bias[c0 + i] : 0.f;
#pragma unroll
        for (int k = 0; k < FIN; ++k) {
            float xk = xrow[k];
            const float* wr = W + (size_t)k * FOUT + c0;
#pragma unroll
            for (int i = 0; i < 8; ++i) a[i] = fmaf(xk, wr[i], a[i]);
        }
        if (OUTRELU) {
#pragma unroll
            for (int i = 0; i < 8; ++i) a[i] = fmaxf(a[i], 0.f);
        }
        if (EXTRA != 2) {
            float4 o0 = {a[0], a[1], a[2], a[3]};
            float4 o1 = {a[4], a[5], a[6], a[7]};
            float4* op = reinterpret_cast<float4*>(out + (size_t)row * FOUT + c0);
            op[0] = o0; op[1] = o1;
        }
        if (EXTRA == 1) {
            uint4 o2 = {bfpack2(dv * fmaxf(a[0], 0.f), dv * fmaxf(a[1], 0.f)),
                        bfpack2(dv * fmaxf(a[2], 0.f), dv * fmaxf(a[3], 0.f)),
                        bfpack2(dv * fmaxf(a[4], 0.f), dv * fmaxf(a[5], 0.f)),
                        bfpack2(dv * fmaxf(a[6], 0.f), dv * fmaxf(a[7], 0.f))};
            *reinterpret_cast<uint4*>(out2b + (size_t)row * (FOUT / 2) + c0 / 2) = o2;
        }
        if (EXTRA == 2) {
            uint4 o2 = {bfpack2(dv * a[0], dv * a[1]),
                        bfpack2(dv * a[2], dv * a[3]),
                        bfpack2(dv * a[4], dv * a[5]),
                        bfpack2(dv * a[6], dv * a[7])};
            *reinterpret_cast<uint4*>(out2b + (size_t)row * (FOUT / 2) + c0 / 2) = o2;
        }
    }
}

// ---------------- segment mean pool ----------------
__global__ __launch_bounds__(THREADS)
void k_pool(const float* __restrict__ h, const int* __restrict__ batch,
            float* __restrict__ sums, float* __restrict__ cnts, int n) {
    int c = threadIdx.x & 63;
    int rq = threadIdx.x >> 6;  // 0..3
    int r0 = blockIdx.x * THREADS;
    int rend = min(r0 + THREADS, n);
    int curg = -1;
    float acc = 0.f, cacc = 0.f;
    for (int r = r0 + rq; r < rend; r += 4) {
        int g = batch[r];
        if (g != curg) {
            if (curg >= 0) {
                atomicAdd(&sums[(size_t)curg * 64 + c], acc);
                if (c == 0) atomicAdd(&cnts[curg], cacc);
            }
            curg = g; acc = 0.f; cacc = 0.f;
        }
        acc += h[(size_t)r * 64 + c];
        cacc += 1.f;
    }
    if (curg >= 0) {
        atomicAdd(&sums[(size_t)curg * 64 + c], acc);
        if (c == 0) atomicAdd(&cnts[curg], cacc);
    }
}

__global__ __launch_bounds__(THREADS)
void k_div(const float* __restrict__ sums, const float* __restrict__ cnts,
           float* __restrict__ out, int total) {
    int i = blockIdx.x * THREADS + threadIdx.x;
    if (i < total) out[i] = sums[i] / cnts[i >> 6];
}

// ---------------------------------------------------------------------------
static inline size_t alignup(size_t v) { return (v + 255) & ~(size_t)255; }

extern "C" void kernel_launch(void* const* d_in, const int* in_sizes, int n_in,
                              void* d_out, int out_size, void* d_ws, size_t ws_size,
                              hipStream_t stream) {
    const float* ev_f  = (const float*)d_in[0];
    const float* cs_f  = (const float*)d_in[1];
    const float* tr_f  = (const float*)d_in[2];
    const float* env_f = (const float*)d_in[3];
    const int*   ei    = (const int*)d_in[4];
    const int*   ev_i  = (const int*)d_in[5];
    const int*   cs_i  = (const int*)d_in[6];
    const int*   tr_i  = (const int*)d_in[7];
    const int*   env_i = (const int*)d_in[8];
    const int*   batch = (const int*)d_in[9];
    const float* W_ev = (const float*)d_in[10]; const float* b_ev = (const float*)d_in[11];
    const float* W_cs = (const float*)d_in[12]; const float* b_cs = (const float*)d_in[13];
    const float* W_tr = (const float*)d_in[14]; const float* b_tr = (const float*)d_in[15];
    const float* W_env= (const float*)d_in[16]; const float* b_env= (const float*)d_in[17];
    const float* W1 = (const float*)d_in[18]; const float* b1 = (const float*)d_in[19];
    const float* W2 = (const float*)d_in[20]; const float* b2 = (const float*)d_in[21];
    const float* W3 = (const float*)d_in[22]; const float* b3 = (const float*)d_in[23];

    const int E_ = in_sizes[4] / 2;
    const int N_ = in_sizes[9];
    const int n_ev  = in_sizes[5];
    const int n_cs  = in_sizes[6];
    const int n_tr  = in_sizes[7];
    const int n_env = in_sizes[8];
    const int ngr   = out_size / 64;  // 100 graphs

    const int* e_src = ei;
    const int* e_dst = ei + E_;

    const int NB   = (N_ + (1 << BINSHIFT) - 1) >> BINSHIFT;  // 98 bins
    const int ablk = (E_ + EPBA - 1) / EPBA;                  // 782 partition blocks

    // ---- workspace carve-up ----
    char* p = (char*)d_ws;
    int*      counts = (int*)p;      p += alignup((size_t)NB * ablk * 4);
    int*      bintot = (int*)p;      p += alignup((size_t)NB * 4);
    int*      binptr = (int*)p;      p += alignup(((size_t)NB + 1) * 4);
    int*      rowptr = (int*)p;      p += alignup(((size_t)N_ + 1) * 4);
    float*    dinv   = (float*)p;    p += alignup((size_t)N_ * 4);
    int*      srcs   = (int*)p;      p += alignup((size_t)E_ * 4);
    unsigned* xb     = (unsigned*)p; p += alignup((size_t)N_ * 16 * 4);   // bf16 [N,32]
    float*    x1     = (float*)p;    p += alignup((size_t)N_ * 64 * 4);
    float*    bufB   = (float*)p;    p += alignup((size_t)N_ * 64 * 4);
    float*    bufA   = (float*)p;    p += alignup((size_t)N_ * 128 * 4);
    float*    sums   = (float*)p;    p += alignup((size_t)ngr * 64 * 4);
    float*    cnts   = (float*)p;    p += alignup((size_t)ngr * 4);

    // Aliases into dead regions:
    //  pairs (E int2 = 25.6 MB)  -> bufA (dies at k_bincsr, bufA written by mm2)
    //  x1s_bf (N*32 u32 = 12.8MB)-> bufA (lives mm1 -> gather2; mm2 writes bufA after)
    //  t3s_bf (N*32 u32 = 12.8MB)-> bufB (bufB dead after mm2 reads it; mm3 writes,
    //                               gather3 reads, gather3 writes bufA)
    int2*     pairs  = (int2*)bufA;
    unsigned* x1s_bf = (unsigned*)bufA;
    unsigned* t3s_bf = (unsigned*)bufB;

    const int nblk = (N_ + THREADS - 1) / THREADS;
    const int gblk = ((size_t)N_ * 64 + THREADS - 1) / THREADS;     // wave/node

    // ---- zero accumulated buffers (fresh every call) ----
    hipMemsetAsync(sums, 0, (size_t)ngr * 64 * 4, stream);
    hipMemsetAsync(cnts, 0, (size_t)ngr * 4, stream);

    // ---- CSR build (atomic-free partition) ----
    k_partcnt<<<ablk, THREADS, (size_t)NB * 4, stream>>>(e_dst, counts, ablk, NB, E_);
    k_scanrows<<<NB, THREADS, 0, stream>>>(counts, bintot, ablk);
    k_binscan<<<1, 128, 0, stream>>>(bintot, binptr, NB, E_);
    k_partwrite<<<ablk, THREADS, (size_t)NB * 8, stream>>>(e_src, e_dst, binptr, counts, ablk, pairs, NB, E_);
    k_bincsr<<<NB, THREADS, 0, stream>>>(pairs, binptr, rowptr, dinv, srcs, N_, NB, E_);

    // ---- embeddings -> xb [N,32] bf16 (pre-scaled by dinv) ----
    k_embed<6><<<((size_t)n_ev  * 16 + THREADS - 1) / THREADS, THREADS, 0, stream>>>(ev_f,  W_ev,  b_ev,  ev_i,  dinv, n_ev,  xb);
    k_embed<4><<<((size_t)n_cs  * 16 + THREADS - 1) / THREADS, THREADS, 0, stream>>>(cs_f,  W_cs,  b_cs,  cs_i,  dinv, n_cs,  xb);
    k_embed<2><<<((size_t)n_tr  * 16 + THREADS - 1) / THREADS, THREADS, 0, stream>>>(tr_f,  W_tr,  b_tr,  tr_i,  dinv, n_tr,  xb);
    k_embed<5><<<((size_t)n_env * 16 + THREADS - 1) / THREADS, THREADS, 0, stream>>>(env_f, W_env, b_env, env_i, dinv, n_env, xb);

    // ---- conv1: agg(xb) @ W1 + b1 -> x1 (f32); x1s_bf = bf16(dinv*relu(x1)) ----
    k_gather32<<<gblk, THREADS, 0, stream>>>(xb, rowptr, srcs, dinv, bufB, N_);
    k_mm<32, 64, 16, true, false, 1><<<dim3(nblk, 4), THREADS, 0, stream>>>(
        bufB, W1, b1, dinv, x1, x1s_bf, N_);

    // ---- conv2: relu( agg(x1s_bf) @ W2 + b2 ) -> bufA [N,128] ----
    k_gather64<false, false, false><<<gblk, THREADS, 0, stream>>>(
        x1s_bf, rowptr, srcs, dinv, nullptr, nullptr, bufB, N_);
    k_mm<64, 128, 32, true, true, 0><<<dim3(nblk, 4), THREADS, 0, stream>>>(
        bufB, W2, b2, nullptr, bufA, nullptr, N_);

    // ---- conv3: t3s_bf = bf16(dinv*(bufA @ W3)); h = relu(agg+b3)+x1 -> bufA ----
    k_mm<128, 64, 32, false, false, 2><<<dim3(nblk, 2), THREADS, 0, stream>>>(
        bufA, W3, nullptr, dinv, nullptr, t3s_bf, N_);
    k_gather64<true, true, true><<<gblk, THREADS, 0, stream>>>(
        t3s_bf, rowptr, srcs, dinv, b3, x1, bufA, N_);

    // ---- pool ----
    k_pool<<<nblk, THREADS, 0, stream>>>(bufA, batch, sums, cnts, N_);
    k_div<<<(out_size + THREADS - 1) / THREADS, THREADS, 0, stream>>>(sums, cnts, (float*)d_out, out_size);
}